// Round 8
// baseline (121.432 us; speedup 1.0000x reference)
//
#include <hip/hip_runtime.h>
#include <hip/hip_cooperative_groups.h>
#include <math.h>

namespace cg = cooperative_groups;

namespace {
constexpr int NB   = 8;    // batch
constexpr int NWIN = 128;  // WIN
constexpr int NK   = 256;  // K (feature/attention dim)
constexpr int NE   = 256;  // E = 2*WIN

// ---------------------------------------------------------------------------
// Phase 1 (projection) as a device function.
//   hi [b][i][e] = sum_w x[b][w][i] * W_lin[e][w]
//   hjT[b][e][j] = sum_w x[b][w][j] * W_lin[e][WIN+w] + b_lin[e]
// block bid -> (b = bid>>6, e-tile of 4); thread t -> (i = t&255, eh = t>>8
// handling 2 of the 4 e's). x loads lane-coalesced; W loads wave-uniform.
// ---------------------------------------------------------------------------
__device__ __forceinline__ void proj_phase(
    const float* __restrict__ x, const float* __restrict__ W,
    const float* __restrict__ bl, float* __restrict__ hi,
    float* __restrict__ hjT, int bid, int t)
{
  const int b  = bid >> 6;
  const int e0 = ((bid & 63) << 2) + ((t >> 8) << 1);  // this thread's 2 e's
  const int i  = t & 255;

  float a1x = 0.f, a1y = 0.f, a2x = 0.f, a2y = 0.f;
  const float* xb = x + (size_t)b * NWIN * NK + i;
  const float* Wr = W + (size_t)e0 * (2 * NWIN);
#pragma unroll 8
  for (int w = 0; w < NWIN; ++w) {
    const float xv = xb[(size_t)w * NK];
    a1x = fmaf(xv, Wr[w], a1x);                  // W1 row e0
    a2x = fmaf(xv, Wr[NWIN + w], a2x);           // W2 row e0
    a1y = fmaf(xv, Wr[2 * NWIN + w], a1y);       // W1 row e0+1
    a2y = fmaf(xv, Wr[3 * NWIN + w], a2y);       // W2 row e0+1
  }
  *reinterpret_cast<float2*>(hi + ((size_t)(b * NK + i)) * NE + e0) =
      make_float2(a1x, a1y);
  hjT[((size_t)(b * NE + e0)) * NK + i]     = a2x + bl[e0];
  hjT[((size_t)(b * NE + e0 + 1)) * NK + i] = a2y + bl[e0 + 1];
}

// ---------------------------------------------------------------------------
// Phase 2 (attention) as a device function — round-7 k2 verbatim.
// block -> (b, i-tile of 4), 512 threads.
// ---------------------------------------------------------------------------
__device__ __forceinline__ void attn_phase(
    const float* __restrict__ x, const float* __restrict__ a_vec,
    const float* __restrict__ bias, const float* __restrict__ hi,
    const float* __restrict__ hjT, float* __restrict__ out,
    int bid, int t, float* smA, float* smB)
{
  const int b    = bid >> 6;
  const int i0   = (bid & 63) << 2;
  const int lane = t & 63, wave = t >> 6;

  // ---- stage hi tile (1024 floats) + 0.8*a ----
  if (t < 256) {
    ((float4*)smA)[t] =
        ((const float4*)(hi + ((size_t)(b * NK + i0)) * NE))[t];
  } else if (t < 320) {
    const float4 av = ((const float4*)a_vec)[t - 256];
    ((float4*)(smA + 1024))[t - 256] =
        make_float4(0.8f * av.x, 0.8f * av.y, 0.8f * av.z, 0.8f * av.w);
  }
  __syncthreads();

  // ---- main relu loop: wave = e-eighth q, lane -> 4 contiguous j ----
  {
    const int q = wave;
    const int j0 = lane << 2;
    float s[4][4];
#pragma unroll
    for (int ii = 0; ii < 4; ++ii)
#pragma unroll
      for (int m = 0; m < 4; ++m) s[ii][m] = 0.f;
    float aj[4] = {0.f, 0.f, 0.f, 0.f};

    const float* hjb = hjT + (size_t)b * NE * NK + j0;

#pragma unroll 2
    for (int ec = 0; ec < 8; ++ec) {
      const int e = q * 32 + ec * 4;
      float h[4][4];  // [k = e-offset][m = j-offset]
#pragma unroll
      for (int k = 0; k < 4; ++k)
        *reinterpret_cast<float4*>(h[k]) =
            *reinterpret_cast<const float4*>(hjb + (size_t)(e + k) * NK);
      float a4[4];
      *reinterpret_cast<float4*>(a4) =
          *reinterpret_cast<const float4*>(smA + 1024 + e);
#pragma unroll
      for (int k = 0; k < 4; ++k)
#pragma unroll
        for (int m = 0; m < 4; ++m) aj[m] = fmaf(a4[k], h[k][m], aj[m]);
#pragma unroll
      for (int ii = 0; ii < 4; ++ii) {
        float g[4];
        *reinterpret_cast<float4*>(g) =
            *reinterpret_cast<const float4*>(smA + ii * NE + e);
#pragma unroll
        for (int k = 0; k < 4; ++k)
#pragma unroll
          for (int m = 0; m < 4; ++m)
            s[ii][m] = fmaf(a4[k], fmaxf(g[k] + h[k][m], 0.f), s[ii][m]);
      }
    }

    // fold 0.25*aj_q into every ii slot; Sum_q gives relu-sum + 0.25*aj.
#pragma unroll
    for (int ii = 0; ii < 4; ++ii)
      *reinterpret_cast<float4*>(&smB[(q * 4 + ii) * NK + j0]) =
          make_float4(s[ii][0] + 0.25f * aj[0], s[ii][1] + 0.25f * aj[1],
                      s[ii][2] + 0.25f * aj[2], s[ii][3] + 0.25f * aj[3]);
  }
  __syncthreads();

  // ---- softmax over j: waves 0-3, wave = row ii (overwrites hi w/ attn) ----
  if (wave < 4) {
    const int ii = wave;
    float ev[4];
    float mmax = -INFINITY;
#pragma unroll
    for (int r = 0; r < 4; ++r) {
      const int jj = lane + 64 * r;
      float v = bias[(size_t)(i0 + ii) * NK + jj];
#pragma unroll
      for (int qq = 0; qq < 8; ++qq) v += smB[(qq * 4 + ii) * NK + jj];
      ev[r] = v;
      mmax = fmaxf(mmax, v);
    }
#pragma unroll
    for (int o = 32; o; o >>= 1) mmax = fmaxf(mmax, __shfl_xor(mmax, o));
    float ssum = 0.f;
#pragma unroll
    for (int r = 0; r < 4; ++r) { ev[r] = __expf(ev[r] - mmax); ssum += ev[r]; }
#pragma unroll
    for (int o = 32; o; o >>= 1) ssum += __shfl_xor(ssum, o);
    const float inv = 1.f / ssum;
#pragma unroll
    for (int r = 0; r < 4; ++r) smA[ii * NE + lane + 64 * r] = ev[r] * inv;
  }
  __syncthreads();

  // ---- PV: thread = (w = t>>2, jq = t&3); 4-lane groups share one x row ----
  {
    const int wv = t >> 2, jq = t & 3;
    float s0 = 0.f, s1 = 0.f, s2 = 0.f, s3 = 0.f;
    const float* xr = x + (size_t)b * NWIN * NK + (size_t)wv * NK;
#pragma unroll 4
    for (int jc = 0; jc < 16; ++jc) {
      const int j = jc * 16 + jq * 4;
      const float4 xv = *reinterpret_cast<const float4*>(&xr[j]);
      const float4 a0 = *reinterpret_cast<const float4*>(&smA[0 * NE + j]);
      const float4 a1 = *reinterpret_cast<const float4*>(&smA[1 * NE + j]);
      const float4 a2 = *reinterpret_cast<const float4*>(&smA[2 * NE + j]);
      const float4 a3 = *reinterpret_cast<const float4*>(&smA[3 * NE + j]);
      s0 = fmaf(a0.x, xv.x, s0); s0 = fmaf(a0.y, xv.y, s0);
      s0 = fmaf(a0.z, xv.z, s0); s0 = fmaf(a0.w, xv.w, s0);
      s1 = fmaf(a1.x, xv.x, s1); s1 = fmaf(a1.y, xv.y, s1);
      s1 = fmaf(a1.z, xv.z, s1); s1 = fmaf(a1.w, xv.w, s1);
      s2 = fmaf(a2.x, xv.x, s2); s2 = fmaf(a2.y, xv.y, s2);
      s2 = fmaf(a2.z, xv.z, s2); s2 = fmaf(a2.w, xv.w, s2);
      s3 = fmaf(a3.x, xv.x, s3); s3 = fmaf(a3.y, xv.y, s3);
      s3 = fmaf(a3.z, xv.z, s3); s3 = fmaf(a3.w, xv.w, s3);
    }
#pragma unroll
    for (int o = 1; o <= 2; o <<= 1) {
      s0 += __shfl_xor(s0, o);
      s1 += __shfl_xor(s1, o);
      s2 += __shfl_xor(s2, o);
      s3 += __shfl_xor(s3, o);
    }
    if (jq == 0) {
      float4 o4;
      o4.x = 1.f / (1.f + __expf(-s0));
      o4.y = 1.f / (1.f + __expf(-s1));
      o4.z = 1.f / (1.f + __expf(-s2));
      o4.w = 1.f / (1.f + __expf(-s3));
      *reinterpret_cast<float4*>(out + ((size_t)(b * NWIN + wv)) * NK + i0) =
          o4;
    }
  }
}

// ---------------------------------------------------------------------------
// Fused cooperative kernel: phase1 -> grid.sync() -> phase2.
// grid = 512 blocks x 512 threads = exactly 2 blocks/CU on 256 CUs.
// ---------------------------------------------------------------------------
__global__ __launch_bounds__(512, 4) void fused(
    const float* __restrict__ x, const float* __restrict__ W,
    const float* __restrict__ bl, const float* __restrict__ a_vec,
    const float* __restrict__ bias, float* __restrict__ hi,
    float* __restrict__ hjT, float* __restrict__ out)
{
  __shared__ __align__(16) float smA[1280];
  __shared__ __align__(16) float smB[8192];

  const int bid = blockIdx.x;
  const int t   = threadIdx.x;

  proj_phase(x, W, bl, hi, hjT, bid, t);
  cg::this_grid().sync();
  attn_phase(x, a_vec, bias, hi, hjT, out, bid, t, smA, smB);
}

// ---------------------------------------------------------------------------
// Fallback pair (round-7 structure) in case cooperative launch is rejected
// under graph capture.
// ---------------------------------------------------------------------------
__global__ __launch_bounds__(512) void k1_proj(
    const float* __restrict__ x, const float* __restrict__ W,
    const float* __restrict__ bl, float* __restrict__ hi,
    float* __restrict__ hjT)
{
  proj_phase(x, W, bl, hi, hjT, blockIdx.x, threadIdx.x);
}

__global__ __launch_bounds__(512, 4) void k2_attn(
    const float* __restrict__ x, const float* __restrict__ a_vec,
    const float* __restrict__ bias, const float* __restrict__ hi,
    const float* __restrict__ hjT, float* __restrict__ out)
{
  __shared__ __align__(16) float smA[1280];
  __shared__ __align__(16) float smB[8192];
  attn_phase(x, a_vec, bias, hi, hjT, out, blockIdx.x, threadIdx.x, smA, smB);
}

}  // namespace

extern "C" void kernel_launch(void* const* d_in, const int* in_sizes, int n_in,
                              void* d_out, int out_size, void* d_ws,
                              size_t ws_size, hipStream_t stream)
{
  const float* x    = (const float*)d_in[0];  // (8,128,256)
  const float* Wlin = (const float*)d_in[1];  // (256,256)
  const float* blin = (const float*)d_in[2];  // (256,)
  const float* avec = (const float*)d_in[3];  // (256,1)
  const float* bias = (const float*)d_in[4];  // (256,256)
  float* out = (float*)d_out;                 // (8,128,256)

  float* hi  = (float*)d_ws;                   // B*K*E floats = 2 MB
  float* hjT = hi + (size_t)NB * NK * NE;      // B*E*K floats = 2 MB

  void* args[] = {(void*)&x, (void*)&Wlin, (void*)&blin, (void*)&avec,
                  (void*)&bias, (void*)&hi, (void*)&hjT, (void*)&out};
  hipError_t err = hipLaunchCooperativeKernel(
      (const void*)&fused, dim3(NB * (NK / 4)), dim3(512), args, 0, stream);
  if (err != hipSuccess) {
    // capture rejected coop launch -> two-kernel fallback (round-7 path)
    k1_proj<<<NB * (NE / 4), 512, 0, stream>>>(x, Wlin, blin, hi, hjT);
    k2_attn<<<NB * (NK / 4), 512, 0, stream>>>(x, avec, bias, hi, hjT, out);
  }
}

// Round 9
// 33.996 us; speedup vs baseline: 3.5719x; 3.5719x over previous
//
#include <hip/hip_runtime.h>
#include <math.h>

namespace {
constexpr int NB   = 8;    // batch
constexpr int NWIN = 128;  // WIN
constexpr int NK   = 256;  // K (feature/attention dim)
constexpr int NE   = 256;  // E = 2*WIN

typedef float v2f __attribute__((ext_vector_type(2)));

// ---------------------------------------------------------------------------
// Kernel 1: projections (round-7 version, unchanged).
//   hi [b][i][e] = sum_w x[b][w][i] * W_lin[e][w]
//   hjT[b][e][j] = sum_w x[b][w][j] * W_lin[e][WIN+w] + b_lin[e]
// ---------------------------------------------------------------------------
__global__ __launch_bounds__(256) void k1_proj(
    const float* __restrict__ x, const float* __restrict__ W,
    const float* __restrict__ bl, float* __restrict__ hi,
    float* __restrict__ hjT)
{
  const int b  = blockIdx.x >> 6;          // 0..7
  const int e0 = (blockIdx.x & 63) << 2;   // 64 groups of 4 e's
  const int i  = threadIdx.x;

  float acc1[4] = {0.f, 0.f, 0.f, 0.f};
  float acc2[4] = {0.f, 0.f, 0.f, 0.f};

  const float* xb = x + (size_t)b * NWIN * NK + i;
  const float* Wr = W + (size_t)e0 * (2 * NWIN);
#pragma unroll 8
  for (int w = 0; w < NWIN; ++w) {
    const float xv = xb[(size_t)w * NK];
#pragma unroll
    for (int k = 0; k < 4; ++k) {
      acc1[k] = fmaf(xv, Wr[k * 2 * NWIN + w], acc1[k]);
      acc2[k] = fmaf(xv, Wr[k * 2 * NWIN + NWIN + w], acc2[k]);
    }
  }

  *reinterpret_cast<float4*>(hi + ((size_t)(b * NK + i)) * NE + e0) =
      make_float4(acc1[0], acc1[1], acc1[2], acc1[3]);
#pragma unroll
  for (int k = 0; k < 4; ++k)
    hjT[((size_t)(b * NE + e0 + k)) * NK + i] = acc2[k] + bl[e0 + k];
}

// ---------------------------------------------------------------------------
// Kernel 2: per (b, i-tile of 4) block, 512 threads, grid = 512
// -> 2 blocks/CU, 4 waves/SIMD. Round-7 structure; main relu loop now packed
// fp32 (v_pk_add/v_pk_fma via ext_vector float2) over the j-pair dim.
// ---------------------------------------------------------------------------
__global__ __launch_bounds__(512, 4) void k2_attn(
    const float* __restrict__ x, const float* __restrict__ a_vec,
    const float* __restrict__ bias, const float* __restrict__ hi,
    const float* __restrict__ hjT, float* __restrict__ out)
{
  // smA: [0..1023] hi tile (4 rows x 256), reused as attn after softmax;
  //      [1024..1279] a8 = 0.8*a.
  __shared__ __align__(16) float smA[1280];
  // smB: sred[8 q][4 ii][256 j] = 32 KB.
  __shared__ __align__(16) float smB[8192];

  const int b    = blockIdx.x >> 6;
  const int i0   = (blockIdx.x & 63) << 2;
  const int t    = threadIdx.x;
  const int lane = t & 63, wave = t >> 6;

  // ---- stage hi tile (1024 floats) + 0.8*a ----
  if (t < 256) {
    ((float4*)smA)[t] =
        ((const float4*)(hi + ((size_t)(b * NK + i0)) * NE))[t];
  } else if (t < 320) {
    const float4 av = ((const float4*)a_vec)[t - 256];
    ((float4*)(smA + 1024))[t - 256] =
        make_float4(0.8f * av.x, 0.8f * av.y, 0.8f * av.z, 0.8f * av.w);
  }
  __syncthreads();

  // ---- main relu loop: wave = e-eighth q, lane -> 4 contiguous j ----
  // packed over j-pairs: s2[ii][p] = {j0+2p, j0+2p+1}
  {
    const int q = wave;
    const int j0 = lane << 2;
    v2f s2[4][2];
#pragma unroll
    for (int ii = 0; ii < 4; ++ii)
#pragma unroll
      for (int p = 0; p < 2; ++p) s2[ii][p] = (v2f)0.f;
    v2f aj2[2] = {(v2f)0.f, (v2f)0.f};

    const float* hjb = hjT + (size_t)b * NE * NK + j0;

#pragma unroll 2
    for (int ec = 0; ec < 8; ++ec) {
      const int e = q * 32 + ec * 4;
      v2f h2[4][2];  // [k = e-offset][p = j-pair]
#pragma unroll
      for (int k = 0; k < 4; ++k) {
        const float4 hv =
            *reinterpret_cast<const float4*>(hjb + (size_t)(e + k) * NK);
        h2[k][0] = (v2f){hv.x, hv.y};
        h2[k][1] = (v2f){hv.z, hv.w};
      }
      float a4[4];
      *reinterpret_cast<float4*>(a4) =
          *reinterpret_cast<const float4*>(smA + 1024 + e);
#pragma unroll
      for (int k = 0; k < 4; ++k) {
        const v2f av = (v2f)a4[k];
#pragma unroll
        for (int p = 0; p < 2; ++p)
          aj2[p] = __builtin_elementwise_fma(av, h2[k][p], aj2[p]);
      }
#pragma unroll
      for (int ii = 0; ii < 4; ++ii) {
        float g[4];
        *reinterpret_cast<float4*>(g) =
            *reinterpret_cast<const float4*>(smA + ii * NE + e);
#pragma unroll
        for (int k = 0; k < 4; ++k) {
          const v2f av = (v2f)a4[k];
          const v2f gv = (v2f)g[k];
#pragma unroll
          for (int p = 0; p < 2; ++p) {
            v2f z = h2[k][p] + gv;                       // v_pk_add_f32
            z = __builtin_elementwise_max(z, (v2f)0.f);  // pk or 2x v_max
            s2[ii][p] = __builtin_elementwise_fma(av, z, s2[ii][p]);
          }
        }
      }
    }

    // fold 0.25*aj_q into every ii slot; Sum_q gives relu-sum + 0.25*aj.
    const v2f qv = (v2f)0.25f;
#pragma unroll
    for (int ii = 0; ii < 4; ++ii) {
      const v2f o0 = __builtin_elementwise_fma(qv, aj2[0], s2[ii][0]);
      const v2f o1 = __builtin_elementwise_fma(qv, aj2[1], s2[ii][1]);
      *reinterpret_cast<float4*>(&smB[(q * 4 + ii) * NK + j0]) =
          make_float4(o0.x, o0.y, o1.x, o1.y);
    }
  }
  __syncthreads();

  // ---- softmax over j: waves 0-3, wave = row ii (overwrites hi w/ attn) ----
  if (wave < 4) {
    const int ii = wave;
    float ev[4];
    float mmax = -INFINITY;
#pragma unroll
    for (int r = 0; r < 4; ++r) {
      const int jj = lane + 64 * r;
      float v = bias[(size_t)(i0 + ii) * NK + jj];
#pragma unroll
      for (int qq = 0; qq < 8; ++qq) v += smB[(qq * 4 + ii) * NK + jj];
      ev[r] = v;
      mmax = fmaxf(mmax, v);
    }
#pragma unroll
    for (int o = 32; o; o >>= 1) mmax = fmaxf(mmax, __shfl_xor(mmax, o));
    float ssum = 0.f;
#pragma unroll
    for (int r = 0; r < 4; ++r) { ev[r] = __expf(ev[r] - mmax); ssum += ev[r]; }
#pragma unroll
    for (int o = 32; o; o >>= 1) ssum += __shfl_xor(ssum, o);
    const float inv = 1.f / ssum;
#pragma unroll
    for (int r = 0; r < 4; ++r) smA[ii * NE + lane + 64 * r] = ev[r] * inv;
  }
  __syncthreads();

  // ---- PV: thread = (w = t>>2, jq = t&3); 4-lane groups share one x row ----
  {
    const int wv = t >> 2, jq = t & 3;
    float s0 = 0.f, s1 = 0.f, s2v = 0.f, s3 = 0.f;
    const float* xr = x + (size_t)b * NWIN * NK + (size_t)wv * NK;
#pragma unroll 4
    for (int jc = 0; jc < 16; ++jc) {
      const int j = jc * 16 + jq * 4;
      const float4 xv = *reinterpret_cast<const float4*>(&xr[j]);
      const float4 a0 = *reinterpret_cast<const float4*>(&smA[0 * NE + j]);
      const float4 a1 = *reinterpret_cast<const float4*>(&smA[1 * NE + j]);
      const float4 a2 = *reinterpret_cast<const float4*>(&smA[2 * NE + j]);
      const float4 a3 = *reinterpret_cast<const float4*>(&smA[3 * NE + j]);
      s0 = fmaf(a0.x, xv.x, s0); s0 = fmaf(a0.y, xv.y, s0);
      s0 = fmaf(a0.z, xv.z, s0); s0 = fmaf(a0.w, xv.w, s0);
      s1 = fmaf(a1.x, xv.x, s1); s1 = fmaf(a1.y, xv.y, s1);
      s1 = fmaf(a1.z, xv.z, s1); s1 = fmaf(a1.w, xv.w, s1);
      s2v = fmaf(a2.x, xv.x, s2v); s2v = fmaf(a2.y, xv.y, s2v);
      s2v = fmaf(a2.z, xv.z, s2v); s2v = fmaf(a2.w, xv.w, s2v);
      s3 = fmaf(a3.x, xv.x, s3); s3 = fmaf(a3.y, xv.y, s3);
      s3 = fmaf(a3.z, xv.z, s3); s3 = fmaf(a3.w, xv.w, s3);
    }
#pragma unroll
    for (int o = 1; o <= 2; o <<= 1) {
      s0 += __shfl_xor(s0, o);
      s1 += __shfl_xor(s1, o);
      s2v += __shfl_xor(s2v, o);
      s3 += __shfl_xor(s3, o);
    }
    if (jq == 0) {
      float4 o4;
      o4.x = 1.f / (1.f + __expf(-s0));
      o4.y = 1.f / (1.f + __expf(-s1));
      o4.z = 1.f / (1.f + __expf(-s2v));
      o4.w = 1.f / (1.f + __expf(-s3));
      *reinterpret_cast<float4*>(out + ((size_t)(b * NWIN + wv)) * NK + i0) =
          o4;
    }
  }
}

}  // namespace

extern "C" void kernel_launch(void* const* d_in, const int* in_sizes, int n_in,
                              void* d_out, int out_size, void* d_ws,
                              size_t ws_size, hipStream_t stream)
{
  const float* x    = (const float*)d_in[0];  // (8,128,256)
  const float* Wlin = (const float*)d_in[1];  // (256,256)
  const float* blin = (const float*)d_in[2];  // (256,)
  const float* avec = (const float*)d_in[3];  // (256,1)
  const float* bias = (const float*)d_in[4];  // (256,256)
  float* out = (float*)d_out;                 // (8,128,256)

  float* hi  = (float*)d_ws;                   // B*K*E floats = 2 MB
  float* hjT = hi + (size_t)NB * NK * NE;      // B*E*K floats = 2 MB

  k1_proj<<<NB * (NE / 4), 256, 0, stream>>>(x, Wlin, blin, hi, hjT);
  k2_attn<<<NB * (NK / 4), 512, 0, stream>>>(x, avec, bias, hi, hjT, out);
}